// Round 8
// baseline (684.874 us; speedup 1.0000x reference)
//
#include <hip/hip_runtime.h>
#include <hip/hip_bf16.h>

#define HH 96
#define WW 96
#define NPX 9216          // HH*WW
#define NC 21             // classes

// bilateral MFMA tiling: block=256 (4 waves); wave = 1 n-tile of 32 j;
// block = 128 j; grid (72 j-blocks, 36 i-chunks of 256); K-steps of 16
#define CH 256
#define NKS 16            // CH/16
#define NCHK 36           // i-chunks (grid.y)
#define JBX 72            // j-blocks (grid.x), 72*128=9216

// rowsum tiling
#define RNI 144
#define RCH 64

// truncated separable gaussian: radius 24 (tail mass ~1.8e-4)
#define RAD2 24
#define TAPS2 49

typedef __attribute__((ext_vector_type(8))) short s8v;
typedef __attribute__((ext_vector_type(16))) float f16v;

// normalized separable 1D gaussian taps g[|d|] (exp(-d^2/72)/S, S=15.03977)
__device__ const float GN[36] = {
    6.64904e-02f, 6.55733e-02f, 6.28973e-02f, 5.86776e-02f, 5.32413e-02f,
    4.69853e-02f, 4.03286e-02f, 3.36665e-02f, 2.73351e-02f, 2.15863e-02f,
    1.65795e-02f, 1.23852e-02f, 8.99851e-03f, 6.35877e-03f, 4.37031e-03f,
    2.92139e-03f, 1.89933e-03f, 1.20102e-03f, 7.38645e-04f, 4.41830e-04f,
    2.57057e-04f, 1.45461e-04f, 8.00452e-05f, 4.28451e-05f, 2.23052e-05f,
    1.12939e-05f, 5.56182e-06f, 2.66396e-06f, 1.24101e-06f, 5.62291e-07f,
    2.47787e-07f, 1.06203e-07f, 4.42716e-08f, 1.79497e-08f, 7.07818e-09f,
    2.71479e-09f
};

__device__ __forceinline__ bool is_bf16(const void* kstd_raw){
    return (((const unsigned int*)kstd_raw)[0] & 0xFFFFu) != 0u;
}
__device__ __forceinline__ float ld_in(const void* p, int i, bool bf){
    if (bf){
        unsigned int u = ((unsigned int)((const unsigned short*)p)[i]) << 16;
        return __uint_as_float(u);
    }
    return ((const float*)p)[i];
}
__device__ __forceinline__ unsigned short f2bf(float f){
    unsigned int u = __float_as_uint(f);
    unsigned int r = u + 0x7FFFu + ((u >> 16) & 1u);   // RNE
    return (unsigned short)(r >> 16);
}

// ---------- setup: features (+|f|^2 in slot5), U=log(clip(u)), q0=softmax(U) ----------
__global__ __launch_bounds__(64) void setup_kernel(const void* __restrict__ unary_raw,
                                                   const void* __restrict__ ref_raw,
                                                   const void* __restrict__ kstd_raw,
                                                   float* __restrict__ feat,
                                                   float* __restrict__ U, float* __restrict__ q,
                                                   float* __restrict__ qbf,
                                                   float* __restrict__ nacc,
                                                   int use_part){
    int i = blockIdx.x*64 + threadIdx.x;
    if (i >= NPX) return;
    bool bf = is_bf16(kstd_raw);
    const float SCL = 0.84932180028801907f; // sqrt(0.5*log2(e))
    int y = i / WW, x = i - y*WW;
    float f0 = (float)y * (SCL / ld_in(kstd_raw, 0, bf));
    float f1 = (float)x * (SCL / ld_in(kstd_raw, 1, bf));
    float f2 = ld_in(ref_raw, 0*NPX+i, bf) * (SCL / ld_in(kstd_raw, 2, bf));
    float f3 = ld_in(ref_raw, 1*NPX+i, bf) * (SCL / ld_in(kstd_raw, 3, bf));
    float f4 = ld_in(ref_raw, 2*NPX+i, bf) * (SCL / ld_in(kstd_raw, 4, bf));
    feat[i*8+0] = f0; feat[i*8+1] = f1; feat[i*8+2] = f2; feat[i*8+3] = f3; feat[i*8+4] = f4;
    feat[i*8+5] = f0*f0 + f1*f1 + f2*f2 + f3*f3 + f4*f4;
    feat[i*8+6] = 0.f; feat[i*8+7] = 0.f;
    nacc[i] = 0.f;

    float u[NC]; float m = -1e30f;
    #pragma unroll
    for (int c = 0; c < NC; ++c){
        float v = ld_in(unary_raw, c*NPX+i, bf);
        v = fminf(fmaxf(v, 1e-5f), 1.0f);
        float lg = logf(v);
        U[c*NPX+i] = lg;
        u[c] = lg;
        m = fmaxf(m, lg);
        if (!use_part) qbf[c*NPX+i] = 0.f;
    }
    float s = 0.f;
    #pragma unroll
    for (int c = 0; c < NC; ++c){ u[c] = expf(u[c]-m); s += u[c]; }
    float inv = 1.f/s;
    #pragma unroll
    for (int c = 0; c < NC; ++c) q[c*NPX+i] = u[c]*inv;
}

// ---------- rowsum of K (for norm): -d2 = -sqj + (-sqi) + sum (2fi)*fj ----------
__global__ __launch_bounds__(256) void rowsum_kernel(const float* __restrict__ feat,
                                                     float* __restrict__ nacc){
    __shared__ __align__(16) float s_feat[RNI*8];
    int tid = threadIdx.x;
    int i0 = blockIdx.y * RNI;
    for (int s = tid; s < RNI*8; s += 256){
        float v = feat[i0*8 + s];
        int sl = s & 7;
        if (sl < 5) v *= 2.0f;
        else if (sl == 5) v = -v;
        s_feat[s] = v;
    }
    __syncthreads();
    int j = blockIdx.x*256 + tid;
    float4 fj = *(const float4*)(feat + j*8);
    float2 fj45 = *(const float2*)(feat + j*8 + 4);
    float fj4 = fj45.x, nsqj = -fj45.y;
    float a = 0.f;
    #pragma unroll 4
    for (int ii = 0; ii < RNI; ++ii){
        const float* sf = s_feat + ii*8;
        float4 f0 = *(const float4*)sf;
        float2 f45 = *(const float2*)(sf+4);
        float t = nsqj + f45.y;
        t = fmaf(fj.x, f0.x, t); t = fmaf(fj.y, f0.y, t); t = fmaf(fj.z, f0.z, t);
        t = fmaf(fj.w, f0.w, t); t = fmaf(fj4, f45.x, t);
        a += __builtin_amdgcn_exp2f(t);
    }
    atomicAdd(&nacc[j], a);
}

__global__ __launch_bounds__(64) void normfin_kernel(const float* __restrict__ nacc,
                                                     float* __restrict__ rnorm){
    int j = blockIdx.x*64 + threadIdx.x;
    if (j >= NPX) return;
    rnorm[j] = 1.0f / (sqrtf(nacc[j]) + 1e-8f);
}

// ---------- horizontal / vertical 1D gaussian conv (zero padded, radius 24) ----------
__global__ __launch_bounds__(256) void convh_kernel(const float* __restrict__ q,
                                                    float* __restrict__ o){
    int idx = blockIdx.x*256 + threadIdx.x;
    if (idx >= NC*NPX) return;
    int c = idx / NPX; int p = idx - c*NPX; int y = p / WW; int x = p - y*WW;
    const float* row = q + c*NPX + y*WW;
    int tlo = max(0, RAD2 - x);
    int thi = min(TAPS2-1, RAD2 + (WW-1) - x);
    float a = 0.f;
    for (int t = tlo; t <= thi; ++t) a += GN[abs(t-RAD2)]*row[x + t - RAD2];
    o[idx] = a;
}

__global__ __launch_bounds__(256) void convv_kernel(const float* __restrict__ q,
                                                    float* __restrict__ o){
    int idx = blockIdx.x*256 + threadIdx.x;
    if (idx >= NC*NPX) return;
    int c = idx / NPX; int p = idx - c*NPX; int y = p / WW; int x = p - y*WW;
    const float* col = q + c*NPX + x;
    int tlo = max(0, RAD2 - y);
    int thi = min(TAPS2-1, RAD2 + (HH-1) - y);
    float a = 0.f;
    for (int t = tlo; t <= thi; ++t) a += GN[abs(t-RAD2)]*col[(y + t - RAD2)*WW];
    o[idx] = a;
}

// ---------- dense bilateral via MFMA: part[chunk][c][j] = sum_{i in chunk} w(i,j)*tmp[c,i] ----------
__global__ __launch_bounds__(256) void bilateral_kernel(const float* __restrict__ q,
                                                        const float* __restrict__ feat,
                                                        const float* __restrict__ rnorm,
                                                        float* __restrict__ qbf,
                                                        float* __restrict__ part,
                                                        int use_part){
    __shared__ __align__(16) float s_feat[CH*8];            // [2f0..2f4, -sq, pad, pad]
    __shared__ __align__(16) unsigned short s_tmpA[CH*32];  // [i>>3][c(32)][i&7] bf16
    int tid = threadIdx.x;
    int i0 = blockIdx.y * CH;
    for (int s = tid; s < CH*8; s += 256){
        float v = feat[(size_t)i0*8 + s];
        int sl = s & 7;
        if (sl < 5) v *= 2.0f;
        else if (sl == 5) v = -v;
        s_feat[s] = v;
    }
    for (int e = tid; e < 32*CH; e += 256){
        int c = e >> 8;            // e / CH (CH=256)
        int i = e & (CH-1);
        float val = (c < NC) ? q[c*NPX + i0 + i] * rnorm[i0 + i] : 0.f;
        s_tmpA[(i>>3)*256 + c*8 + (i&7)] = f2bf(val);
    }
    __syncthreads();

    int lane = tid & 63;
    int wv = tid >> 6;
    int jwb = blockIdx.x*128 + wv*32;
    int jl = lane & 31;
    int half = lane >> 5;

    const float* fp = feat + (size_t)(jwb + jl)*8;
    float4 fj03 = *(const float4*)fp;
    float2 fpt = *(const float2*)(fp+4);
    float fj4 = fpt.x, nsqj = -fpt.y;

    f16v acc;
    #pragma unroll
    for (int r = 0; r < 16; ++r) acc[r] = 0.f;

    for (int kc = 0; kc < NKS; ++kc){
        s8v afrag = *(const s8v*)(s_tmpA + (kc*2 + half)*256 + jl*8);
        union { s8v v; __hip_bfloat162 h[4]; } bfr;
        #pragma unroll
        for (int p = 0; p < 4; ++p){
            const float* sf0 = s_feat + (kc*16 + half*8 + p*2    )*8;
            const float* sf1 = s_feat + (kc*16 + half*8 + p*2 + 1)*8;
            float4 a03 = *(const float4*)sf0; float2 a45 = *(const float2*)(sf0+4);
            float4 b03 = *(const float4*)sf1; float2 b45 = *(const float2*)(sf1+4);
            float t0 = nsqj + a45.y;
            t0 = fmaf(fj03.x, a03.x, t0); t0 = fmaf(fj03.y, a03.y, t0);
            t0 = fmaf(fj03.z, a03.z, t0); t0 = fmaf(fj03.w, a03.w, t0);
            t0 = fmaf(fj4,    a45.x, t0);
            float t1 = nsqj + b45.y;
            t1 = fmaf(fj03.x, b03.x, t1); t1 = fmaf(fj03.y, b03.y, t1);
            t1 = fmaf(fj03.z, b03.z, t1); t1 = fmaf(fj03.w, b03.w, t1);
            t1 = fmaf(fj4,    b45.x, t1);
            float w0 = __builtin_amdgcn_exp2f(t0);
            float w1 = __builtin_amdgcn_exp2f(t1);
            bfr.h[p] = __float22bfloat162_rn(make_float2(w0, w1));
        }
        acc = __builtin_amdgcn_mfma_f32_32x32x16_bf16(afrag, bfr.v, acc, 0, 0, 0);
    }
    // C layout: col=j=lane&31, row=c=(reg&3)+8*(reg>>2)+4*(lane>>5)
    int j = jwb + jl;
    if (use_part){
        float* dst = part + (size_t)blockIdx.y * (NC*NPX);
        #pragma unroll
        for (int r = 0; r < 16; ++r){
            int c = (r&3) + 8*(r>>2) + 4*half;
            if (c < NC) dst[c*NPX + j] = acc[r];
        }
    } else {
        #pragma unroll
        for (int r = 0; r < 16; ++r){
            int c = (r&3) + 8*(r>>2) + 4*half;
            if (c < NC) atomicAdd(&qbf[c*NPX + j], acc[r]);
        }
    }
}

// ---------- combine: qbf_j = sum_chunks part ; q_hat = U + 4*qbf*rn + 2*qsf ; softmax ----------
__global__ __launch_bounds__(64) void combine_kernel(const float* __restrict__ U,
                                                     float* __restrict__ qbf,
                                                     const float* __restrict__ part,
                                                     const float* __restrict__ qsf,
                                                     const float* __restrict__ rnorm,
                                                     float* __restrict__ qn,
                                                     void* __restrict__ outp,
                                                     const void* __restrict__ kstd_raw,
                                                     int use_part){
    int j = blockIdx.x*64 + threadIdx.x;
    if (j >= NPX) return;
    float rn4 = 4.0f * rnorm[j];
    float h[NC]; float m = -1e30f;
    #pragma unroll
    for (int c = 0; c < NC; ++c){
        float b;
        if (use_part){
            b = 0.f;
            #pragma unroll
            for (int ch = 0; ch < NCHK; ++ch) b += part[(size_t)ch*(NC*NPX) + c*NPX + j];
        } else {
            b = qbf[c*NPX+j];
            qbf[c*NPX+j] = 0.f;
        }
        float v = U[c*NPX+j] + b*rn4 + 2.0f*qsf[c*NPX+j];
        h[c] = v; m = fmaxf(m, v);
    }
    float s = 0.f;
    #pragma unroll
    for (int c = 0; c < NC; ++c){ h[c] = expf(h[c]-m); s += h[c]; }
    float inv = 1.f/s;
    bool bf = outp ? is_bf16(kstd_raw) : false;
    #pragma unroll
    for (int c = 0; c < NC; ++c){
        float v = h[c]*inv;
        qn[c*NPX+j] = v;
        if (outp){
            if (bf) ((__hip_bfloat16*)outp)[c*NPX+j] = __float2bfloat16(v);
            else    ((float*)outp)[c*NPX+j] = v;
        }
    }
}

extern "C" void kernel_launch(void* const* d_in, const int* in_sizes, int n_in,
                              void* d_out, int out_size, void* d_ws, size_t ws_size,
                              hipStream_t stream) {
    const void* unary_raw = d_in[0];
    const void* ref_raw   = d_in[1];
    const void* kstd_raw  = d_in[2];

    float* w = (float*)d_ws;
    float* feat  = w; w += NPX*8;
    float* U     = w; w += NC*NPX;
    float* qA    = w; w += NC*NPX;
    float* qB    = w; w += NC*NPX;
    float* t1b   = w; w += NC*NPX;
    float* qsf   = w; w += NC*NPX;
    float* qbf   = w; w += NC*NPX;
    float* nacc  = w; w += NPX;
    float* rnorm = w; w += NPX;
    float* part  = w; w += (size_t)NCHK*NC*NPX;

    // partial-sum path needs ~33 MB of workspace; ws_size is launch-constant,
    // so this branch is identical every call (graph-capture safe).
    size_t need = (size_t)((char*)w - (char*)d_ws);
    int use_part = (ws_size >= need) ? 1 : 0;

    hipLaunchKernelGGL(setup_kernel, dim3(144), dim3(64), 0, stream,
                       unary_raw, ref_raw, kstd_raw, feat, U, qA, qbf, nacc, use_part);
    hipLaunchKernelGGL(rowsum_kernel, dim3(36, RCH), dim3(256), 0, stream, feat, nacc);
    hipLaunchKernelGGL(normfin_kernel, dim3(144), dim3(64), 0, stream, nacc, rnorm);

    float* qc = qA; float* qn = qB;
    for (int it = 0; it < 5; ++it){
        hipLaunchKernelGGL(convh_kernel, dim3(756), dim3(256), 0, stream, qc, t1b);
        hipLaunchKernelGGL(convv_kernel, dim3(756), dim3(256), 0, stream, t1b, qsf);
        hipLaunchKernelGGL(bilateral_kernel, dim3(JBX, NCHK), dim3(256), 0, stream,
                           qc, feat, rnorm, qbf, part, use_part);
        hipLaunchKernelGGL(combine_kernel, dim3(144), dim3(64), 0, stream,
                           U, qbf, part, qsf, rnorm, qn,
                           (it == 4) ? d_out : (void*)nullptr, kstd_raw, use_part);
        float* tswap = qc; qc = qn; qn = tswap;
    }
}

// Round 9
// 369.077 us; speedup vs baseline: 1.8556x; 1.8556x over previous
//
#include <hip/hip_runtime.h>
#include <hip/hip_bf16.h>

#define HH 96
#define WW 96
#define NPX 9216          // HH*WW
#define NC 21             // classes

// bilateral MFMA tiling: block=256 (4 waves); wave = 2 n-tiles of 32 j = 64 j;
// block = 256 j; grid (36 j-blocks, 36 i-chunks of 256); K-steps of 16
#define CH 256
#define NKS 16            // CH/16
#define NCHK 36           // i-chunks (grid.y)
#define JBX 36            // j-blocks (grid.x), 36*256=9216
#define NT 2
#define TROW 264          // padded A-staging row stride in shorts (killed 16-way write conflict)

// rowsum tiling
#define RNI 144
#define RCH 64

// truncated separable gaussian: radius 24 (tail mass ~1.8e-4)
#define RAD2 24
#define TAPS2 49

typedef __attribute__((ext_vector_type(8))) short s8v;
typedef __attribute__((ext_vector_type(16))) float f16v;

// normalized separable 1D gaussian taps g[|d|] (exp(-d^2/72)/S, S=15.03977)
__device__ const float GN[36] = {
    6.64904e-02f, 6.55733e-02f, 6.28973e-02f, 5.86776e-02f, 5.32413e-02f,
    4.69853e-02f, 4.03286e-02f, 3.36665e-02f, 2.73351e-02f, 2.15863e-02f,
    1.65795e-02f, 1.23852e-02f, 8.99851e-03f, 6.35877e-03f, 4.37031e-03f,
    2.92139e-03f, 1.89933e-03f, 1.20102e-03f, 7.38645e-04f, 4.41830e-04f,
    2.57057e-04f, 1.45461e-04f, 8.00452e-05f, 4.28451e-05f, 2.23052e-05f,
    1.12939e-05f, 5.56182e-06f, 2.66396e-06f, 1.24101e-06f, 5.62291e-07f,
    2.47787e-07f, 1.06203e-07f, 4.42716e-08f, 1.79497e-08f, 7.07818e-09f,
    2.71479e-09f
};

__device__ __forceinline__ bool is_bf16(const void* kstd_raw){
    return (((const unsigned int*)kstd_raw)[0] & 0xFFFFu) != 0u;
}
__device__ __forceinline__ float ld_in(const void* p, int i, bool bf){
    if (bf){
        unsigned int u = ((unsigned int)((const unsigned short*)p)[i]) << 16;
        return __uint_as_float(u);
    }
    return ((const float*)p)[i];
}
__device__ __forceinline__ unsigned short f2bf(float f){
    unsigned int u = __float_as_uint(f);
    unsigned int r = u + 0x7FFFu + ((u >> 16) & 1u);   // RNE
    return (unsigned short)(r >> 16);
}

// ---------- setup: features (+|f|^2 in slot5), U=log(clip(u)), q0=softmax(U) ----------
__global__ __launch_bounds__(64) void setup_kernel(const void* __restrict__ unary_raw,
                                                   const void* __restrict__ ref_raw,
                                                   const void* __restrict__ kstd_raw,
                                                   float* __restrict__ feat,
                                                   float* __restrict__ U, float* __restrict__ q,
                                                   float* __restrict__ qbf,
                                                   float* __restrict__ nacc,
                                                   int use_part){
    int i = blockIdx.x*64 + threadIdx.x;
    if (i >= NPX) return;
    bool bf = is_bf16(kstd_raw);
    const float SCL = 0.84932180028801907f; // sqrt(0.5*log2(e))
    int y = i / WW, x = i - y*WW;
    float f0 = (float)y * (SCL / ld_in(kstd_raw, 0, bf));
    float f1 = (float)x * (SCL / ld_in(kstd_raw, 1, bf));
    float f2 = ld_in(ref_raw, 0*NPX+i, bf) * (SCL / ld_in(kstd_raw, 2, bf));
    float f3 = ld_in(ref_raw, 1*NPX+i, bf) * (SCL / ld_in(kstd_raw, 3, bf));
    float f4 = ld_in(ref_raw, 2*NPX+i, bf) * (SCL / ld_in(kstd_raw, 4, bf));
    feat[i*8+0] = f0; feat[i*8+1] = f1; feat[i*8+2] = f2; feat[i*8+3] = f3; feat[i*8+4] = f4;
    feat[i*8+5] = f0*f0 + f1*f1 + f2*f2 + f3*f3 + f4*f4;
    feat[i*8+6] = 0.f; feat[i*8+7] = 0.f;
    nacc[i] = 0.f;

    float u[NC]; float m = -1e30f;
    #pragma unroll
    for (int c = 0; c < NC; ++c){
        float v = ld_in(unary_raw, c*NPX+i, bf);
        v = fminf(fmaxf(v, 1e-5f), 1.0f);
        float lg = logf(v);
        U[c*NPX+i] = lg;
        u[c] = lg;
        m = fmaxf(m, lg);
        if (!use_part) qbf[c*NPX+i] = 0.f;
    }
    float s = 0.f;
    #pragma unroll
    for (int c = 0; c < NC; ++c){ u[c] = expf(u[c]-m); s += u[c]; }
    float inv = 1.f/s;
    #pragma unroll
    for (int c = 0; c < NC; ++c) q[c*NPX+i] = u[c]*inv;
}

// ---------- rowsum of K (for norm): -d2 = -sqj + (-sqi) + sum (2fi)*fj ----------
__global__ __launch_bounds__(256) void rowsum_kernel(const float* __restrict__ feat,
                                                     float* __restrict__ nacc){
    __shared__ __align__(16) float s_feat[RNI*8];
    int tid = threadIdx.x;
    int i0 = blockIdx.y * RNI;
    for (int s = tid; s < RNI*8; s += 256){
        float v = feat[i0*8 + s];
        int sl = s & 7;
        if (sl < 5) v *= 2.0f;
        else if (sl == 5) v = -v;
        s_feat[s] = v;
    }
    __syncthreads();
    int j = blockIdx.x*256 + tid;
    float4 fj = *(const float4*)(feat + j*8);
    float2 fj45 = *(const float2*)(feat + j*8 + 4);
    float fj4 = fj45.x, nsqj = -fj45.y;
    float a = 0.f;
    #pragma unroll 4
    for (int ii = 0; ii < RNI; ++ii){
        const float* sf = s_feat + ii*8;
        float4 f0 = *(const float4*)sf;
        float2 f45 = *(const float2*)(sf+4);
        float t = nsqj + f45.y;
        t = fmaf(fj.x, f0.x, t); t = fmaf(fj.y, f0.y, t); t = fmaf(fj.z, f0.z, t);
        t = fmaf(fj.w, f0.w, t); t = fmaf(fj4, f45.x, t);
        a += __builtin_amdgcn_exp2f(t);
    }
    atomicAdd(&nacc[j], a);
}

__global__ __launch_bounds__(64) void normfin_kernel(const float* __restrict__ nacc,
                                                     float* __restrict__ rnorm){
    int j = blockIdx.x*64 + threadIdx.x;
    if (j >= NPX) return;
    rnorm[j] = 1.0f / (sqrtf(nacc[j]) + 1e-8f);
}

// ---------- horizontal conv: 4 outputs/thread, uniform 52-tap window, clamp+select ----------
__global__ __launch_bounds__(256) void convh_kernel(const float* __restrict__ q,
                                                    float* __restrict__ o){
    int gid = blockIdx.x*256 + threadIdx.x;           // 189*256 = 48384 = NC*NPX/4
    int c   = gid / 2304;
    int rem = gid - c*2304;
    int y   = rem / 24;
    int x0  = (rem - y*24) * 4;
    const float* row = q + c*NPX + y*WW;
    float a0 = 0.f, a1 = 0.f, a2 = 0.f, a3 = 0.f;
    #pragma unroll
    for (int t = 0; t < 52; ++t){
        int xx = x0 + t - RAD2;
        int xc = min(max(xx, 0), WW-1);
        float v = row[xc];
        v = ((unsigned)xx < (unsigned)WW) ? v : 0.f;
        if (t <= 48)           a0 = fmaf(GN[abs(t     - RAD2)], v, a0);
        if (t >= 1 && t <= 49) a1 = fmaf(GN[abs(t - 1 - RAD2)], v, a1);
        if (t >= 2 && t <= 50) a2 = fmaf(GN[abs(t - 2 - RAD2)], v, a2);
        if (t >= 3)            a3 = fmaf(GN[abs(t - 3 - RAD2)], v, a3);
    }
    float* op = o + c*NPX + y*WW + x0;
    op[0] = a0; op[1] = a1; op[2] = a2; op[3] = a3;
}

// ---------- vertical conv: 4 outputs/thread (consecutive y), coalesced across x ----------
__global__ __launch_bounds__(256) void convv_kernel(const float* __restrict__ q,
                                                    float* __restrict__ o){
    int gid = blockIdx.x*256 + threadIdx.x;           // 48384
    int c   = gid / 2304;
    int rem = gid - c*2304;
    int x   = rem % WW;
    int y0  = (rem / WW) * 4;
    const float* col = q + c*NPX + x;
    float a0 = 0.f, a1 = 0.f, a2 = 0.f, a3 = 0.f;
    #pragma unroll
    for (int t = 0; t < 52; ++t){
        int yy = y0 + t - RAD2;
        int yc = min(max(yy, 0), HH-1);
        float v = col[yc*WW];
        v = ((unsigned)yy < (unsigned)HH) ? v : 0.f;
        if (t <= 48)           a0 = fmaf(GN[abs(t     - RAD2)], v, a0);
        if (t >= 1 && t <= 49) a1 = fmaf(GN[abs(t - 1 - RAD2)], v, a1);
        if (t >= 2 && t <= 50) a2 = fmaf(GN[abs(t - 2 - RAD2)], v, a2);
        if (t >= 3)            a3 = fmaf(GN[abs(t - 3 - RAD2)], v, a3);
    }
    float* op = o + c*NPX + x;
    op[(y0+0)*WW] = a0; op[(y0+1)*WW] = a1; op[(y0+2)*WW] = a2; op[(y0+3)*WW] = a3;
}

// ---------- dense bilateral via MFMA: part[chunk][c][j] = sum_{i in chunk} w(i,j)*tmp[c,i] ----------
__global__ __launch_bounds__(256) void bilateral_kernel(const float* __restrict__ q,
                                                        const float* __restrict__ feat,
                                                        const float* __restrict__ rnorm,
                                                        float* __restrict__ qbf,
                                                        float* __restrict__ part,
                                                        int use_part){
    __shared__ __align__(16) float s_feat[CH*8];              // [2f0..2f4, -sq, pad, pad]
    __shared__ __align__(16) unsigned short s_tmpA[(CH/8)*TROW]; // [i>>3][c*8+(i&7)], padded rows
    int tid = threadIdx.x;
    int i0 = blockIdx.y * CH;
    for (int s = tid; s < CH*8; s += 256){
        float v = feat[(size_t)i0*8 + s];
        int sl = s & 7;
        if (sl < 5) v *= 2.0f;
        else if (sl == 5) v = -v;
        s_feat[s] = v;
    }
    for (int e = tid; e < 32*CH; e += 256){
        int c = e >> 8;            // e / CH (CH=256)
        int i = e & (CH-1);
        float val = (c < NC) ? q[c*NPX + i0 + i] * rnorm[i0 + i] : 0.f;
        s_tmpA[(i>>3)*TROW + c*8 + (i&7)] = f2bf(val);
    }
    __syncthreads();

    int lane = tid & 63;
    int wv = tid >> 6;
    int jwb = blockIdx.x*256 + wv*64;
    int jl = lane & 31;
    int half = lane >> 5;

    float4 fj03[NT]; float fj4[NT], nsqj[NT];
    #pragma unroll
    for (int n = 0; n < NT; ++n){
        const float* fp = feat + (size_t)(jwb + n*32 + jl)*8;
        fj03[n] = *(const float4*)fp;
        float2 t = *(const float2*)(fp+4);
        fj4[n] = t.x; nsqj[n] = -t.y;
    }
    f16v acc[NT];
    #pragma unroll
    for (int n = 0; n < NT; ++n)
        #pragma unroll
        for (int r = 0; r < 16; ++r) acc[n][r] = 0.f;

    for (int kc = 0; kc < NKS; ++kc){
        s8v afrag = *(const s8v*)(s_tmpA + (kc*2 + half)*TROW + jl*8);
        union { s8v v; __hip_bfloat162 h[4]; } bfr[NT];
        #pragma unroll
        for (int p = 0; p < 4; ++p){
            const float* sf0 = s_feat + (kc*16 + half*8 + p*2    )*8;
            const float* sf1 = s_feat + (kc*16 + half*8 + p*2 + 1)*8;
            float4 a03 = *(const float4*)sf0; float2 a45 = *(const float2*)(sf0+4);
            float4 b03 = *(const float4*)sf1; float2 b45 = *(const float2*)(sf1+4);
            #pragma unroll
            for (int n = 0; n < NT; ++n){
                float t0 = nsqj[n] + a45.y;
                t0 = fmaf(fj03[n].x, a03.x, t0); t0 = fmaf(fj03[n].y, a03.y, t0);
                t0 = fmaf(fj03[n].z, a03.z, t0); t0 = fmaf(fj03[n].w, a03.w, t0);
                t0 = fmaf(fj4[n],    a45.x, t0);
                float t1 = nsqj[n] + b45.y;
                t1 = fmaf(fj03[n].x, b03.x, t1); t1 = fmaf(fj03[n].y, b03.y, t1);
                t1 = fmaf(fj03[n].z, b03.z, t1); t1 = fmaf(fj03[n].w, b03.w, t1);
                t1 = fmaf(fj4[n],    b45.x, t1);
                float w0 = __builtin_amdgcn_exp2f(t0);
                float w1 = __builtin_amdgcn_exp2f(t1);
                bfr[n].h[p] = __float22bfloat162_rn(make_float2(w0, w1));
            }
        }
        #pragma unroll
        for (int n = 0; n < NT; ++n)
            acc[n] = __builtin_amdgcn_mfma_f32_32x32x16_bf16(afrag, bfr[n].v, acc[n], 0, 0, 0);
    }
    // C layout: col=j=lane&31, row=c=(reg&3)+8*(reg>>2)+4*(lane>>5)
    if (use_part){
        float* dst = part + (size_t)blockIdx.y * (NC*NPX);
        #pragma unroll
        for (int n = 0; n < NT; ++n){
            int j = jwb + n*32 + jl;
            #pragma unroll
            for (int r = 0; r < 16; ++r){
                int c = (r&3) + 8*(r>>2) + 4*half;
                if (c < NC) dst[c*NPX + j] = acc[n][r];
            }
        }
    } else {
        #pragma unroll
        for (int n = 0; n < NT; ++n){
            int j = jwb + n*32 + jl;
            #pragma unroll
            for (int r = 0; r < 16; ++r){
                int c = (r&3) + 8*(r>>2) + 4*half;
                if (c < NC) atomicAdd(&qbf[c*NPX + j], acc[n][r]);
            }
        }
    }
}

// ---------- sum the 36 chunk-partials into qbf ----------
__global__ __launch_bounds__(256) void reduce_kernel(const float* __restrict__ part,
                                                     float* __restrict__ qbf){
    int idx = blockIdx.x*256 + threadIdx.x;
    if (idx >= NC*NPX) return;
    float s = 0.f;
    #pragma unroll
    for (int ch = 0; ch < NCHK; ++ch) s += part[(size_t)ch*(NC*NPX) + idx];
    qbf[idx] = s;
}

// ---------- q_hat = U + 4*qbf*rnorm_j + 2*qsf ; softmax; zero qbf (atomic path) ----------
__global__ __launch_bounds__(256) void combine_kernel(const float* __restrict__ U,
                                                      float* __restrict__ qbf,
                                                      const float* __restrict__ qsf,
                                                      const float* __restrict__ rnorm,
                                                      float* __restrict__ qn,
                                                      void* __restrict__ outp,
                                                      const void* __restrict__ kstd_raw,
                                                      int use_part){
    int j = blockIdx.x*256 + threadIdx.x;
    if (j >= NPX) return;
    float rn4 = 4.0f * rnorm[j];
    float h[NC]; float m = -1e30f;
    #pragma unroll
    for (int c = 0; c < NC; ++c){
        float b = qbf[c*NPX+j];
        if (!use_part) qbf[c*NPX+j] = 0.f;
        float v = U[c*NPX+j] + b*rn4 + 2.0f*qsf[c*NPX+j];
        h[c] = v; m = fmaxf(m, v);
    }
    float s = 0.f;
    #pragma unroll
    for (int c = 0; c < NC; ++c){ h[c] = expf(h[c]-m); s += h[c]; }
    float inv = 1.f/s;
    bool bf = outp ? is_bf16(kstd_raw) : false;
    #pragma unroll
    for (int c = 0; c < NC; ++c){
        float v = h[c]*inv;
        qn[c*NPX+j] = v;
        if (outp){
            if (bf) ((__hip_bfloat16*)outp)[c*NPX+j] = __float2bfloat16(v);
            else    ((float*)outp)[c*NPX+j] = v;
        }
    }
}

extern "C" void kernel_launch(void* const* d_in, const int* in_sizes, int n_in,
                              void* d_out, int out_size, void* d_ws, size_t ws_size,
                              hipStream_t stream) {
    const void* unary_raw = d_in[0];
    const void* ref_raw   = d_in[1];
    const void* kstd_raw  = d_in[2];

    float* w = (float*)d_ws;
    float* feat  = w; w += NPX*8;
    float* U     = w; w += NC*NPX;
    float* qA    = w; w += NC*NPX;
    float* qB    = w; w += NC*NPX;
    float* t1b   = w; w += NC*NPX;
    float* qsf   = w; w += NC*NPX;
    float* qbf   = w; w += NC*NPX;
    float* nacc  = w; w += NPX;
    float* rnorm = w; w += NPX;
    float* part  = w; w += (size_t)NCHK*NC*NPX;

    // partial-sum path needs ~33 MB of workspace; ws_size is launch-constant,
    // so this branch is identical every call (graph-capture safe).
    size_t need = (size_t)((char*)w - (char*)d_ws);
    int use_part = (ws_size >= need) ? 1 : 0;

    hipLaunchKernelGGL(setup_kernel, dim3(144), dim3(64), 0, stream,
                       unary_raw, ref_raw, kstd_raw, feat, U, qA, qbf, nacc, use_part);
    hipLaunchKernelGGL(rowsum_kernel, dim3(36, RCH), dim3(256), 0, stream, feat, nacc);
    hipLaunchKernelGGL(normfin_kernel, dim3(144), dim3(64), 0, stream, nacc, rnorm);

    float* qc = qA; float* qn = qB;
    for (int it = 0; it < 5; ++it){
        hipLaunchKernelGGL(convh_kernel, dim3(189), dim3(256), 0, stream, qc, t1b);
        hipLaunchKernelGGL(convv_kernel, dim3(189), dim3(256), 0, stream, t1b, qsf);
        hipLaunchKernelGGL(bilateral_kernel, dim3(JBX, NCHK), dim3(256), 0, stream,
                           qc, feat, rnorm, qbf, part, use_part);
        if (use_part)
            hipLaunchKernelGGL(reduce_kernel, dim3(756), dim3(256), 0, stream, part, qbf);
        hipLaunchKernelGGL(combine_kernel, dim3(36), dim3(256), 0, stream,
                           U, qbf, qsf, rnorm, qn,
                           (it == 4) ? d_out : (void*)nullptr, kstd_raw, use_part);
        float* tswap = qc; qc = qn; qn = tswap;
    }
}

// Round 10
// 365.042 us; speedup vs baseline: 1.8762x; 1.0111x over previous
//
#include <hip/hip_runtime.h>
#include <hip/hip_bf16.h>

#define HH 96
#define WW 96
#define NPX 9216          // HH*WW
#define NC 21             // classes

// bilateral MFMA tiling: block=256 (4 waves); wave = 2 n-tiles of 32 j = 64 j;
// block = 256 j; grid (36 j-blocks, 36 i-chunks of 256)
// d2 computed by MFMA over K=32 split-bf16 feature channels; W half-swapped via ds_bpermute
#define CH 256
#define NCHK 36           // i-chunks (grid.y)
#define JBX 36            // j-blocks (grid.x), 36*256=9216
#define NT 2
#define TROW 264          // padded tmp-staging row stride in shorts

// rowsum tiling
#define RNI 144
#define RCH 64

// truncated separable gaussian: radius 24 (tail mass ~1.8e-4)
#define RAD2 24
#define TAPS2 49

typedef __attribute__((ext_vector_type(8))) short s8v;
typedef __attribute__((ext_vector_type(16))) float f16v;

// normalized separable 1D gaussian taps g[|d|] (exp(-d^2/72)/S, S=15.03977)
__device__ const float GN[36] = {
    6.64904e-02f, 6.55733e-02f, 6.28973e-02f, 5.86776e-02f, 5.32413e-02f,
    4.69853e-02f, 4.03286e-02f, 3.36665e-02f, 2.73351e-02f, 2.15863e-02f,
    1.65795e-02f, 1.23852e-02f, 8.99851e-03f, 6.35877e-03f, 4.37031e-03f,
    2.92139e-03f, 1.89933e-03f, 1.20102e-03f, 7.38645e-04f, 4.41830e-04f,
    2.57057e-04f, 1.45461e-04f, 8.00452e-05f, 4.28451e-05f, 2.23052e-05f,
    1.12939e-05f, 5.56182e-06f, 2.66396e-06f, 1.24101e-06f, 5.62291e-07f,
    2.47787e-07f, 1.06203e-07f, 4.42716e-08f, 1.79497e-08f, 7.07818e-09f,
    2.71479e-09f
};

__device__ __forceinline__ bool is_bf16(const void* kstd_raw){
    return (((const unsigned int*)kstd_raw)[0] & 0xFFFFu) != 0u;
}
__device__ __forceinline__ float ld_in(const void* p, int i, bool bf){
    if (bf){
        unsigned int u = ((unsigned int)((const unsigned short*)p)[i]) << 16;
        return __uint_as_float(u);
    }
    return ((const float*)p)[i];
}
__device__ __forceinline__ unsigned short f2bf(float f){
    unsigned int u = __float_as_uint(f);
    unsigned int r = u + 0x7FFFu + ((u >> 16) & 1u);   // RNE
    return (unsigned short)(r >> 16);
}
__device__ __forceinline__ float bf2float(unsigned short h){
    return __uint_as_float(((unsigned)h) << 16);
}

// ---------- setup: features (+|f|^2 in slot5), U=log(clip(u)), q0=softmax(U) ----------
__global__ __launch_bounds__(64) void setup_kernel(const void* __restrict__ unary_raw,
                                                   const void* __restrict__ ref_raw,
                                                   const void* __restrict__ kstd_raw,
                                                   float* __restrict__ feat,
                                                   float* __restrict__ U, float* __restrict__ q,
                                                   float* __restrict__ qbf,
                                                   float* __restrict__ nacc,
                                                   int use_part){
    int i = blockIdx.x*64 + threadIdx.x;
    if (i >= NPX) return;
    bool bf = is_bf16(kstd_raw);
    const float SCL = 0.84932180028801907f; // sqrt(0.5*log2(e))
    int y = i / WW, x = i - y*WW;
    float f0 = (float)y * (SCL / ld_in(kstd_raw, 0, bf));
    float f1 = (float)x * (SCL / ld_in(kstd_raw, 1, bf));
    float f2 = ld_in(ref_raw, 0*NPX+i, bf) * (SCL / ld_in(kstd_raw, 2, bf));
    float f3 = ld_in(ref_raw, 1*NPX+i, bf) * (SCL / ld_in(kstd_raw, 3, bf));
    float f4 = ld_in(ref_raw, 2*NPX+i, bf) * (SCL / ld_in(kstd_raw, 4, bf));
    feat[i*8+0] = f0; feat[i*8+1] = f1; feat[i*8+2] = f2; feat[i*8+3] = f3; feat[i*8+4] = f4;
    feat[i*8+5] = f0*f0 + f1*f1 + f2*f2 + f3*f3 + f4*f4;
    feat[i*8+6] = 0.f; feat[i*8+7] = 0.f;
    nacc[i] = 0.f;

    float u[NC]; float m = -1e30f;
    #pragma unroll
    for (int c = 0; c < NC; ++c){
        float v = ld_in(unary_raw, c*NPX+i, bf);
        v = fminf(fmaxf(v, 1e-5f), 1.0f);
        float lg = logf(v);
        U[c*NPX+i] = lg;
        u[c] = lg;
        m = fmaxf(m, lg);
        if (!use_part) qbf[c*NPX+i] = 0.f;
    }
    float s = 0.f;
    #pragma unroll
    for (int c = 0; c < NC; ++c){ u[c] = expf(u[c]-m); s += u[c]; }
    float inv = 1.f/s;
    #pragma unroll
    for (int c = 0; c < NC; ++c) q[c*NPX+i] = u[c]*inv;
}

// ---------- rowsum of K (for norm): -d2 = -sqj + (-sqi) + sum (2fi)*fj ----------
__global__ __launch_bounds__(256) void rowsum_kernel(const float* __restrict__ feat,
                                                     float* __restrict__ nacc){
    __shared__ __align__(16) float s_feat[RNI*8];
    int tid = threadIdx.x;
    int i0 = blockIdx.y * RNI;
    for (int s = tid; s < RNI*8; s += 256){
        float v = feat[i0*8 + s];
        int sl = s & 7;
        if (sl < 5) v *= 2.0f;
        else if (sl == 5) v = -v;
        s_feat[s] = v;
    }
    __syncthreads();
    int j = blockIdx.x*256 + tid;
    float4 fj = *(const float4*)(feat + j*8);
    float2 fj45 = *(const float2*)(feat + j*8 + 4);
    float fj4 = fj45.x, nsqj = -fj45.y;
    float a = 0.f;
    #pragma unroll 4
    for (int ii = 0; ii < RNI; ++ii){
        const float* sf = s_feat + ii*8;
        float4 f0 = *(const float4*)sf;
        float2 f45 = *(const float2*)(sf+4);
        float t = nsqj + f45.y;
        t = fmaf(fj.x, f0.x, t); t = fmaf(fj.y, f0.y, t); t = fmaf(fj.z, f0.z, t);
        t = fmaf(fj.w, f0.w, t); t = fmaf(fj4, f45.x, t);
        a += __builtin_amdgcn_exp2f(t);
    }
    atomicAdd(&nacc[j], a);
}

__global__ __launch_bounds__(64) void normfin_kernel(const float* __restrict__ nacc,
                                                     float* __restrict__ rnorm){
    int j = blockIdx.x*64 + threadIdx.x;
    if (j >= NPX) return;
    rnorm[j] = 1.0f / (sqrtf(nacc[j]) + 1e-8f);
}

// ---------- horizontal conv: 4 outputs/thread, uniform 52-tap window, clamp+select ----------
__global__ __launch_bounds__(256) void convh_kernel(const float* __restrict__ q,
                                                    float* __restrict__ o){
    int gid = blockIdx.x*256 + threadIdx.x;           // 189*256 = 48384 = NC*NPX/4
    int c   = gid / 2304;
    int rem = gid - c*2304;
    int y   = rem / 24;
    int x0  = (rem - y*24) * 4;
    const float* row = q + c*NPX + y*WW;
    float a0 = 0.f, a1 = 0.f, a2 = 0.f, a3 = 0.f;
    #pragma unroll
    for (int t = 0; t < 52; ++t){
        int xx = x0 + t - RAD2;
        int xc = min(max(xx, 0), WW-1);
        float v = row[xc];
        v = ((unsigned)xx < (unsigned)WW) ? v : 0.f;
        if (t <= 48)           a0 = fmaf(GN[abs(t     - RAD2)], v, a0);
        if (t >= 1 && t <= 49) a1 = fmaf(GN[abs(t - 1 - RAD2)], v, a1);
        if (t >= 2 && t <= 50) a2 = fmaf(GN[abs(t - 2 - RAD2)], v, a2);
        if (t >= 3)            a3 = fmaf(GN[abs(t - 3 - RAD2)], v, a3);
    }
    float* op = o + c*NPX + y*WW + x0;
    op[0] = a0; op[1] = a1; op[2] = a2; op[3] = a3;
}

// ---------- vertical conv: 4 outputs/thread (consecutive y), coalesced across x ----------
__global__ __launch_bounds__(256) void convv_kernel(const float* __restrict__ q,
                                                    float* __restrict__ o){
    int gid = blockIdx.x*256 + threadIdx.x;           // 48384
    int c   = gid / 2304;
    int rem = gid - c*2304;
    int x   = rem % WW;
    int y0  = (rem / WW) * 4;
    const float* col = q + c*NPX + x;
    float a0 = 0.f, a1 = 0.f, a2 = 0.f, a3 = 0.f;
    #pragma unroll
    for (int t = 0; t < 52; ++t){
        int yy = y0 + t - RAD2;
        int yc = min(max(yy, 0), HH-1);
        float v = col[yc*WW];
        v = ((unsigned)yy < (unsigned)HH) ? v : 0.f;
        if (t <= 48)           a0 = fmaf(GN[abs(t     - RAD2)], v, a0);
        if (t >= 1 && t <= 49) a1 = fmaf(GN[abs(t - 1 - RAD2)], v, a1);
        if (t >= 2 && t <= 50) a2 = fmaf(GN[abs(t - 2 - RAD2)], v, a2);
        if (t >= 3)            a3 = fmaf(GN[abs(t - 3 - RAD2)], v, a3);
    }
    float* op = o + c*NPX + x;
    op[(y0+0)*WW] = a0; op[(y0+1)*WW] = a1; op[(y0+2)*WW] = a2; op[(y0+3)*WW] = a3;
}

// ---------- dense bilateral, both GEMMs on MFMA ----------
// d2 GEMM channels (K=32, 26 used): per dim d: (2h_i,h_j),(2h_i,l_j),(2l_i,h_j),(2l_i,l_j);
// k20-22: (-sq split_i, 1); k23-25: (1, -sq split_j).  C = 2 f_i.f_j - sq_i - sq_j = -d2.
// W = exp2(C) packed to bf16 pairs, half-swapped via ds_bpermute into B-frag for W@tmp GEMM.
__global__ __launch_bounds__(256, 4) void bilateral_kernel(const float* __restrict__ q,
                                                           const float* __restrict__ feat,
                                                           const float* __restrict__ rnorm,
                                                           float* __restrict__ qbf,
                                                           float* __restrict__ part,
                                                           int use_part){
    __shared__ __align__(16) unsigned short s_featA[4*CH*8];     // [koct][i][8] 16 KB
    __shared__ __align__(16) unsigned short s_tmpA[(CH/8)*TROW]; // [i>>3][c*8+(i&7)] padded
    int tid = threadIdx.x;
    int i0 = blockIdx.y * CH;

    // ---- stage i-side A-channels (one i per thread) ----
    {
        int i = tid;
        const float* fp = feat + (size_t)(i0+i)*8;
        float4 f03 = *(const float4*)fp; float2 f45 = *(const float2*)(fp+4);
        float f[5] = {f03.x, f03.y, f03.z, f03.w, f45.x};
        float sq = f45.y;
        unsigned short ach[32];
        #pragma unroll
        for (int d = 0; d < 5; ++d){
            unsigned short h = f2bf(f[d]);
            float hf = bf2float(h);
            unsigned short l = f2bf(f[d] - hf);
            float lf = bf2float(l);
            unsigned short h2 = f2bf(2.f*hf);
            unsigned short l2 = f2bf(2.f*lf);
            ach[4*d+0]=h2; ach[4*d+1]=h2; ach[4*d+2]=l2; ach[4*d+3]=l2;
        }
        unsigned short s1 = f2bf(sq); float s1f = bf2float(s1);
        unsigned short s2 = f2bf(sq - s1f); float s2f = bf2float(s2);
        unsigned short s3 = f2bf(sq - s1f - s2f);
        ach[20] = (unsigned short)(s1 ^ 0x8000u);
        ach[21] = (unsigned short)(s2 ^ 0x8000u);
        ach[22] = (unsigned short)(s3 ^ 0x8000u);
        ach[23] = 0x3F80u; ach[24] = 0x3F80u; ach[25] = 0x3F80u;
        #pragma unroll
        for (int k = 26; k < 32; ++k) ach[k] = 0;
        #pragma unroll
        for (int ko = 0; ko < 4; ++ko){
            s8v v;
            #pragma unroll
            for (int t = 0; t < 8; ++t) v[t] = (short)ach[ko*8+t];
            *(s8v*)(s_featA + (ko*CH + i)*8) = v;
        }
    }
    // ---- stage tmp (second-GEMM A operand) ----
    for (int e = tid; e < 32*CH; e += 256){
        int c = e >> 8;
        int i = e & (CH-1);
        float val = (c < NC) ? q[c*NPX + i0 + i] * rnorm[i0 + i] : 0.f;
        s_tmpA[(i>>3)*TROW + c*8 + (i&7)] = f2bf(val);
    }

    int lane = tid & 63;
    int wv = tid >> 6;
    int half = lane >> 5;
    int jl = lane & 31;
    int jwb = blockIdx.x*256 + wv*64;
    int pa = (lane ^ 32) << 2;

    // ---- j-side B-channel fragments per n-tile (registers only) ----
    s8v bf0[NT], bf1[NT];
    #pragma unroll
    for (int n = 0; n < NT; ++n){
        const float* fp = feat + (size_t)(jwb + n*32 + jl)*8;
        float4 f03 = *(const float4*)fp; float2 f45 = *(const float2*)(fp+4);
        float f[5] = {f03.x, f03.y, f03.z, f03.w, f45.x};
        float sq = f45.y;
        unsigned short bch[32];
        #pragma unroll
        for (int d = 0; d < 5; ++d){
            unsigned short h = f2bf(f[d]);
            float hf = bf2float(h);
            unsigned short l = f2bf(f[d] - hf);
            bch[4*d+0]=h; bch[4*d+1]=l; bch[4*d+2]=h; bch[4*d+3]=l;
        }
        unsigned short s1 = f2bf(sq); float s1f = bf2float(s1);
        unsigned short s2 = f2bf(sq - s1f); float s2f = bf2float(s2);
        unsigned short s3 = f2bf(sq - s1f - s2f);
        bch[20] = 0x3F80u; bch[21] = 0x3F80u; bch[22] = 0x3F80u;
        bch[23] = (unsigned short)(s1 ^ 0x8000u);
        bch[24] = (unsigned short)(s2 ^ 0x8000u);
        bch[25] = (unsigned short)(s3 ^ 0x8000u);
        #pragma unroll
        for (int k = 26; k < 32; ++k) bch[k] = 0;
        #pragma unroll
        for (int t = 0; t < 8; ++t){
            bf0[n][t] = (short)(half ? bch[8+t]  : bch[t]);
            bf1[n][t] = (short)(half ? bch[24+t] : bch[16+t]);
        }
    }

    f16v zf;
    #pragma unroll
    for (int r = 0; r < 16; ++r) zf[r] = 0.f;
    f16v acc[NT];
    #pragma unroll
    for (int n = 0; n < NT; ++n) acc[n] = zf;

    __syncthreads();

    for (int b = 0; b < 8; ++b){
        s8v af0 = *(const s8v*)(s_featA + (((0+half)*CH + b*32 + jl))*8);
        s8v af1 = *(const s8v*)(s_featA + (((2+half)*CH + b*32 + jl))*8);
        s8v at0 = *(const s8v*)(s_tmpA + (b*4 +     half)*TROW + jl*8);
        s8v at1 = *(const s8v*)(s_tmpA + (b*4 + 2 + half)*TROW + jl*8);
        #pragma unroll
        for (int n = 0; n < NT; ++n){
            f16v c1 = __builtin_amdgcn_mfma_f32_32x32x16_bf16(af0, bf0[n], zf, 0, 0, 0);
            c1 = __builtin_amdgcn_mfma_f32_32x32x16_bf16(af1, bf1[n], c1, 0, 0, 0);
            unsigned P[8], SW[8];
            #pragma unroll
            for (int p = 0; p < 8; ++p){
                float w0 = __builtin_amdgcn_exp2f(c1[2*p]);
                float w1 = __builtin_amdgcn_exp2f(c1[2*p+1]);
                union { __hip_bfloat162 h2; unsigned u; } pk;
                pk.h2 = __float22bfloat162_rn(make_float2(w0, w1));
                P[p] = pk.u;
            }
            #pragma unroll
            for (int p = 0; p < 8; ++p)
                SW[p] = (unsigned)__builtin_amdgcn_ds_bpermute(pa, (int)P[p]);
            union { s8v v; unsigned u[4]; } w1f, w2f;
            w1f.u[0] = half ? SW[2] : P[0];
            w1f.u[1] = half ? SW[3] : P[1];
            w1f.u[2] = half ? P[2]  : SW[0];
            w1f.u[3] = half ? P[3]  : SW[1];
            w2f.u[0] = half ? SW[6] : P[4];
            w2f.u[1] = half ? SW[7] : P[5];
            w2f.u[2] = half ? P[6]  : SW[4];
            w2f.u[3] = half ? P[7]  : SW[5];
            acc[n] = __builtin_amdgcn_mfma_f32_32x32x16_bf16(at0, w1f.v, acc[n], 0, 0, 0);
            acc[n] = __builtin_amdgcn_mfma_f32_32x32x16_bf16(at1, w2f.v, acc[n], 0, 0, 0);
        }
    }
    // C layout: col=j=lane&31, row=c=(reg&3)+8*(reg>>2)+4*(lane>>5)
    if (use_part){
        float* dst = part + (size_t)blockIdx.y * (NC*NPX);
        #pragma unroll
        for (int n = 0; n < NT; ++n){
            int j = jwb + n*32 + jl;
            #pragma unroll
            for (int r = 0; r < 16; ++r){
                int c = (r&3) + 8*(r>>2) + 4*half;
                if (c < NC) dst[c*NPX + j] = acc[n][r];
            }
        }
    } else {
        #pragma unroll
        for (int n = 0; n < NT; ++n){
            int j = jwb + n*32 + jl;
            #pragma unroll
            for (int r = 0; r < 16; ++r){
                int c = (r&3) + 8*(r>>2) + 4*half;
                if (c < NC) atomicAdd(&qbf[c*NPX + j], acc[n][r]);
            }
        }
    }
}

// ---------- sum the 36 chunk-partials into qbf ----------
__global__ __launch_bounds__(256) void reduce_kernel(const float* __restrict__ part,
                                                     float* __restrict__ qbf){
    int idx = blockIdx.x*256 + threadIdx.x;
    if (idx >= NC*NPX) return;
    float s = 0.f;
    #pragma unroll
    for (int ch = 0; ch < NCHK; ++ch) s += part[(size_t)ch*(NC*NPX) + idx];
    qbf[idx] = s;
}

// ---------- q_hat = U + 4*qbf*rnorm_j + 2*qsf ; softmax; zero qbf (atomic path) ----------
__global__ __launch_bounds__(64) void combine_kernel(const float* __restrict__ U,
                                                     float* __restrict__ qbf,
                                                     const float* __restrict__ qsf,
                                                     const float* __restrict__ rnorm,
                                                     float* __restrict__ qn,
                                                     void* __restrict__ outp,
                                                     const void* __restrict__ kstd_raw,
                                                     int use_part){
    int j = blockIdx.x*64 + threadIdx.x;
    if (j >= NPX) return;
    float rn4 = 4.0f * rnorm[j];
    float h[NC]; float m = -1e30f;
    #pragma unroll
    for (int c = 0; c < NC; ++c){
        float b = qbf[c*NPX+j];
        if (!use_part) qbf[c*NPX+j] = 0.f;
        float v = U[c*NPX+j] + b*rn4 + 2.0f*qsf[c*NPX+j];
        h[c] = v; m = fmaxf(m, v);
    }
    float s = 0.f;
    #pragma unroll
    for (int c = 0; c < NC; ++c){ h[c] = expf(h[c]-m); s += h[c]; }
    float inv = 1.f/s;
    bool bf = outp ? is_bf16(kstd_raw) : false;
    #pragma unroll
    for (int c = 0; c < NC; ++c){
        float v = h[c]*inv;
        qn[c*NPX+j] = v;
        if (outp){
            if (bf) ((__hip_bfloat16*)outp)[c*NPX+j] = __float2bfloat16(v);
            else    ((float*)outp)[c*NPX+j] = v;
        }
    }
}

extern "C" void kernel_launch(void* const* d_in, const int* in_sizes, int n_in,
                              void* d_out, int out_size, void* d_ws, size_t ws_size,
                              hipStream_t stream) {
    const void* unary_raw = d_in[0];
    const void* ref_raw   = d_in[1];
    const void* kstd_raw  = d_in[2];

    float* w = (float*)d_ws;
    float* feat  = w; w += NPX*8;
    float* U     = w; w += NC*NPX;
    float* qA    = w; w += NC*NPX;
    float* qB    = w; w += NC*NPX;
    float* t1b   = w; w += NC*NPX;
    float* qsf   = w; w += NC*NPX;
    float* qbf   = w; w += NC*NPX;
    float* nacc  = w; w += NPX;
    float* rnorm = w; w += NPX;
    float* part  = w; w += (size_t)NCHK*NC*NPX;

    // partial-sum path needs ~33 MB of workspace; ws_size is launch-constant,
    // so this branch is identical every call (graph-capture safe).
    size_t need = (size_t)((char*)w - (char*)d_ws);
    int use_part = (ws_size >= need) ? 1 : 0;

    hipLaunchKernelGGL(setup_kernel, dim3(144), dim3(64), 0, stream,
                       unary_raw, ref_raw, kstd_raw, feat, U, qA, qbf, nacc, use_part);
    hipLaunchKernelGGL(rowsum_kernel, dim3(36, RCH), dim3(256), 0, stream, feat, nacc);
    hipLaunchKernelGGL(normfin_kernel, dim3(144), dim3(64), 0, stream, nacc, rnorm);

    float* qc = qA; float* qn = qB;
    for (int it = 0; it < 5; ++it){
        hipLaunchKernelGGL(convh_kernel, dim3(189), dim3(256), 0, stream, qc, t1b);
        hipLaunchKernelGGL(convv_kernel, dim3(189), dim3(256), 0, stream, t1b, qsf);
        hipLaunchKernelGGL(bilateral_kernel, dim3(JBX, NCHK), dim3(256), 0, stream,
                           qc, feat, rnorm, qbf, part, use_part);
        if (use_part)
            hipLaunchKernelGGL(reduce_kernel, dim3(756), dim3(256), 0, stream, part, qbf);
        hipLaunchKernelGGL(combine_kernel, dim3(144), dim3(64), 0, stream,
                           U, qbf, qsf, rnorm, qn,
                           (it == 4) ? d_out : (void*)nullptr, kstd_raw, use_part);
        float* tswap = qc; qc = qn; qn = tswap;
    }
}